// Round 2
// baseline (34.792 us; speedup 1.0000x reference)
//
#include <hip/hip_runtime.h>

// BinaryPositionEmbedding: out[t, :] = sum over set bits i of x[t] of w[i, :]
// x: (4, 8192) int32 -> 32768 tokens; w: (13, 1024) f32; out: (4,8192,1024) f32
//
// Write-bound streaming kernel. Each thread owns a fixed float4 d-chunk and
// keeps all 13 weight float4s in registers; each block handles 16 contiguous
// tokens so stores are 64 KB contiguous coalesced chunks.

#define NBITS 13
#define DMOD 1024
#define TOK_PER_BLOCK 16

typedef float f32x4 __attribute__((ext_vector_type(4)));

__global__ __launch_bounds__(256) void BinaryPositionEmbedding_kernel(
    const int* __restrict__ x, const float* __restrict__ w,
    float* __restrict__ out, int n_tokens) {
    const int t = threadIdx.x;          // 0..255 -> float4 chunk of the 1024 dims
    const int d0 = t * 4;

    // Load this thread's slice of the weight table into registers (13 x f32x4).
    f32x4 wr[NBITS];
#pragma unroll
    for (int i = 0; i < NBITS; ++i) {
        wr[i] = *reinterpret_cast<const f32x4*>(&w[i * DMOD + d0]);
    }

    const int tok0 = blockIdx.x * TOK_PER_BLOCK;
#pragma unroll
    for (int k = 0; k < TOK_PER_BLOCK; ++k) {
        const int tok = tok0 + k;
        if (tok >= n_tokens) break;
        const int pos = x[tok];         // block-uniform -> scalar load

        f32x4 s = {0.f, 0.f, 0.f, 0.f};
#pragma unroll
        for (int i = 0; i < NBITS; ++i) {
            const float b = (float)((pos >> i) & 1);   // uniform bit -> 0.0/1.0
            s.x = fmaf(b, wr[i].x, s.x);
            s.y = fmaf(b, wr[i].y, s.y);
            s.z = fmaf(b, wr[i].z, s.z);
            s.w = fmaf(b, wr[i].w, s.w);
        }

        f32x4* dst = reinterpret_cast<f32x4*>(&out[(size_t)tok * DMOD + d0]);
        __builtin_nontemporal_store(s, dst);
    }
}

extern "C" void kernel_launch(void* const* d_in, const int* in_sizes, int n_in,
                              void* d_out, int out_size, void* d_ws, size_t ws_size,
                              hipStream_t stream) {
    const int* x = (const int*)d_in[0];     // 32768 int32 positions
    const float* w = (const float*)d_in[1]; // 13 x 1024 f32
    float* out = (float*)d_out;             // 32768 x 1024 f32

    const int n_tokens = in_sizes[0];
    const int blocks = (n_tokens + TOK_PER_BLOCK - 1) / TOK_PER_BLOCK;
    BinaryPositionEmbedding_kernel<<<blocks, 256, 0, stream>>>(x, w, out, n_tokens);
}